// Round 1
// baseline (632.445 us; speedup 1.0000x reference)
//
#include <hip/hip_runtime.h>
#include <math.h>

#define B      2048
#define NRELS  512
#define FEAT   300
#define LAT    512

// ======================= top-k / bottom-k =======================
__global__ __launch_bounds__(256) void topk_kernel(const float* __restrict__ logits,
                                                   int* __restrict__ top_idx,
                                                   int* __restrict__ dis_idx)
{
    int lane = threadIdx.x & 63;
    int row  = blockIdx.x * 4 + (threadIdx.x >> 6);
    const float* p = logits + (size_t)row * NRELS;
    float v[8];
#pragma unroll
    for (int j = 0; j < 8; ++j) v[j] = p[j * 64 + lane];

    float w[8];
    // bottom-20 (top_k of -logits): smallest values, smaller index wins ties
#pragma unroll
    for (int j = 0; j < 8; ++j) w[j] = v[j];
    for (int t = 0; t < 20; ++t) {
        float bv = __builtin_inff(); int bi = 0x7fffffff;
#pragma unroll
        for (int j = 0; j < 8; ++j) {
            int idx = j * 64 + lane;
            if (w[j] < bv || (w[j] == bv && idx < bi)) { bv = w[j]; bi = idx; }
        }
#pragma unroll
        for (int off = 32; off >= 1; off >>= 1) {
            float ov = __shfl_xor(bv, off);
            int   oi = __shfl_xor(bi, off);
            if (ov < bv || (ov == bv && oi < bi)) { bv = ov; bi = oi; }
        }
        if ((bi & 63) == lane) w[bi >> 6] = __builtin_inff();
        if (lane == 0) dis_idx[row * 20 + t] = bi;
    }
    // top-3
#pragma unroll
    for (int j = 0; j < 8; ++j) w[j] = v[j];
    for (int t = 0; t < 3; ++t) {
        float bv = -__builtin_inff(); int bi = 0x7fffffff;
#pragma unroll
        for (int j = 0; j < 8; ++j) {
            int idx = j * 64 + lane;
            if (w[j] > bv || (w[j] == bv && idx < bi)) { bv = w[j]; bi = idx; }
        }
#pragma unroll
        for (int off = 32; off >= 1; off >>= 1) {
            float ov = __shfl_xor(bv, off);
            int   oi = __shfl_xor(bi, off);
            if (ov > bv || (ov == bv && oi < bi)) { bv = ov; bi = oi; }
        }
        if ((bi & 63) == lane) w[bi >> 6] = -__builtin_inff();
        if (lane == 0) top_idx[row * 3 + t] = bi;
    }
}

// ======================= gathers =======================
__global__ void gather_R(const int* __restrict__ rels, const float* __restrict__ rel_dict,
                         float* __restrict__ R)
{
    int j = blockIdx.x;                       // 0..511
    int id = rels[2 * j + 1];
    const float* src = rel_dict + (size_t)id * FEAT;
    for (int c = threadIdx.x; c < FEAT; c += blockDim.x)
        R[(size_t)j * FEAT + c] = src[c];
}

__global__ void gather_xcat(const int* __restrict__ rels, const float* __restrict__ rel_dict,
                            const int* __restrict__ top_idx, float* __restrict__ xcat)
{
    int b = blockIdx.x;                       // 0..B-1
    int i0 = rels[2 * top_idx[b * 3 + 0] + 1];
    int i1 = rels[2 * top_idx[b * 3 + 1] + 1];
    int i2 = rels[2 * top_idx[b * 3 + 2] + 1];
    const float* r0 = rel_dict + (size_t)i0 * FEAT;
    const float* r1 = rel_dict + (size_t)i1 * FEAT;
    const float* r2 = rel_dict + (size_t)i2 * FEAT;
    float* dst = xcat + (size_t)b * 600;
    for (int c = threadIdx.x; c < FEAT; c += blockDim.x) {
        float a = r0[c];
        dst[c]        = a * r1[c] * r2[c];   // x
        dst[300 + c]  = a;                   // pos1
    }
}

// ======================= generic tiled f32 GEMM =======================
// C[M,N] = act(A[M,K] @ W[K,N] + bias[N]);  M multiple of 64.
#define BM 64
#define BN 64
#define BK 16

template<int ACT>   // 0 none, 1 relu, 2 leaky(0.2), 3 sigmoid
__global__ __launch_bounds__(256) void gemm_act(const float* __restrict__ A,
                                                const float* __restrict__ W,
                                                const float* __restrict__ bias,
                                                float* __restrict__ C,
                                                int M, int N, int K)
{
    __shared__ float As[BK][BM + 4];
    __shared__ float Ws[BK][BN + 4];
    const int tid  = threadIdx.y * 16 + threadIdx.x;
    const int row0 = blockIdx.y * BM;
    const int col0 = blockIdx.x * BN;

    float acc[4][4] = {};

    for (int k0 = 0; k0 < K; k0 += BK) {
        // A tile: 64 rows x 16 k ; thread loads 4 consecutive k of one row
        {
            int idx  = tid * 4;
            int r    = idx >> 4;
            int k    = idx & 15;
            int grow = row0 + r;
            if (k0 + BK <= K) {
                const float4 v = *reinterpret_cast<const float4*>(&A[(size_t)grow * K + k0 + k]);
                As[k + 0][r] = v.x; As[k + 1][r] = v.y; As[k + 2][r] = v.z; As[k + 3][r] = v.w;
            } else {
#pragma unroll
                for (int u = 0; u < 4; ++u) {
                    int kk = k0 + k + u;
                    As[k + u][r] = (kk < K) ? A[(size_t)grow * K + kk] : 0.f;
                }
            }
        }
        // W tile: 16 k x 64 n
#pragma unroll
        for (int i = 0; i < 4; ++i) {
            int idx = i * 256 + tid;
            int k   = idx >> 6;
            int n   = idx & 63;
            int gk = k0 + k, gn = col0 + n;
            Ws[k][n] = (gk < K && gn < N) ? W[(size_t)gk * N + gn] : 0.f;
        }
        __syncthreads();
#pragma unroll
        for (int kk = 0; kk < BK; ++kk) {
            const float4 av = *reinterpret_cast<const float4*>(&As[kk][threadIdx.y * 4]);
            const float4 wv = *reinterpret_cast<const float4*>(&Ws[kk][threadIdx.x * 4]);
            acc[0][0] += av.x * wv.x; acc[0][1] += av.x * wv.y; acc[0][2] += av.x * wv.z; acc[0][3] += av.x * wv.w;
            acc[1][0] += av.y * wv.x; acc[1][1] += av.y * wv.y; acc[1][2] += av.y * wv.z; acc[1][3] += av.y * wv.w;
            acc[2][0] += av.z * wv.x; acc[2][1] += av.z * wv.y; acc[2][2] += av.z * wv.z; acc[2][3] += av.z * wv.w;
            acc[3][0] += av.w * wv.x; acc[3][1] += av.w * wv.y; acc[3][2] += av.w * wv.z; acc[3][3] += av.w * wv.w;
        }
        __syncthreads();
    }

#pragma unroll
    for (int i = 0; i < 4; ++i) {
        int gr = row0 + threadIdx.y * 4 + i;
#pragma unroll
        for (int j = 0; j < 4; ++j) {
            int gc = col0 + threadIdx.x * 4 + j;
            if (gc < N) {
                float vv = acc[i][j] + bias[gc];
                if (ACT == 1) vv = vv > 0.f ? vv : 0.f;
                else if (ACT == 2) vv = vv > 0.f ? vv : 0.2f * vv;
                else if (ACT == 3) vv = 1.f / (1.f + expf(-vv));
                C[(size_t)gr * N + gc] = vv;
            }
        }
    }
}

// ======================= sampling + KL =======================
__global__ __launch_bounds__(256) void sample_kernel(const float* __restrict__ mu,
                                                     const float* __restrict__ ls,
                                                     const float* __restrict__ eps1,
                                                     const float* __restrict__ eps2,
                                                     float* __restrict__ zcat,
                                                     float* __restrict__ zb,
                                                     float* __restrict__ acc)
{
    float klsum = 0.f;
    const int total = B * LAT;
    for (int i = blockIdx.x * blockDim.x + threadIdx.x; i < total; i += gridDim.x * blockDim.x) {
        int r = i >> 9, c = i & 511;
        float m = mu[i], l = ls[i];
        float s = expf(l);
        zcat[(size_t)r * 812 + c] = m + eps1[i] * s;   // z  (eps1) -> decoder
        zb[i]                     = m + eps2[i] * s;   // z_ (eps2) -> qz encoder
        klsum += -0.5f * (1.f + 2.f * l - m * m - expf(2.f * l));
    }
    __shared__ float red[256];
    red[threadIdx.x] = klsum;
    __syncthreads();
    for (int s = 128; s > 0; s >>= 1) {
        if (threadIdx.x < s) red[threadIdx.x] += red[threadIdx.x + s];
        __syncthreads();
    }
    if (threadIdx.x == 0) atomicAdd(&acc[0], red[0]);
}

__global__ __launch_bounds__(256) void pos1copy_kernel(const float* __restrict__ xcat,
                                                       float* __restrict__ zcat)
{
    const int total = B * FEAT;
    for (int i = blockIdx.x * blockDim.x + threadIdx.x; i < total; i += gridDim.x * blockDim.x) {
        int r = i / FEAT, c = i - r * FEAT;
        zcat[(size_t)r * 812 + 512 + c] = xcat[(size_t)r * 600 + 300 + c];
    }
}

// ======================= recon loss =======================
__global__ __launch_bounds__(256) void recon_loss_kernel(const float* __restrict__ recon,
                                                         const float* __restrict__ xcat,
                                                         float* __restrict__ acc)
{
    float sum = 0.f;
    const int total = B * FEAT;
    for (int i = blockIdx.x * blockDim.x + threadIdx.x; i < total; i += gridDim.x * blockDim.x) {
        int r = i / FEAT, c = i - r * FEAT;
        float d = recon[i] - xcat[(size_t)r * 600 + c];
        sum += d * d;
    }
    __shared__ float red[256];
    red[threadIdx.x] = sum;
    __syncthreads();
    for (int s = 128; s > 0; s >>= 1) {
        if (threadIdx.x < s) red[threadIdx.x] += red[threadIdx.x + s];
        __syncthreads();
    }
    if (threadIdx.x == 0) atomicAdd(&acc[1], red[0]);
}

// ======================= contrastive loss =======================
__global__ __launch_bounds__(256) void csl_kernel(const float* __restrict__ zp,  // rows 1..B of z_rel
                                                  const float* __restrict__ E,
                                                  const int* __restrict__ top_idx,
                                                  const int* __restrict__ dis_idx,
                                                  float* __restrict__ acc)
{
    int lane = threadIdx.x & 63;
    int r    = blockIdx.x * 4 + (threadIdx.x >> 6);
    const float* z = zp + (size_t)r * LAT;
    const float4 za = reinterpret_cast<const float4*>(z)[lane * 2 + 0];
    const float4 zb = reinterpret_cast<const float4*>(z)[lane * 2 + 1];

    int ids[21];
    ids[0] = top_idx[r * 3];
#pragma unroll
    for (int n = 0; n < 20; ++n) ids[n + 1] = dis_idx[r * 20 + n];

    float lg[21];
#pragma unroll
    for (int t = 0; t < 21; ++t) {
        const float* e = E + (size_t)ids[t] * LAT;
        const float4 ea = reinterpret_cast<const float4*>(e)[lane * 2 + 0];
        const float4 eb = reinterpret_cast<const float4*>(e)[lane * 2 + 1];
        float d = za.x * ea.x + za.y * ea.y + za.z * ea.z + za.w * ea.w
                + zb.x * eb.x + zb.y * eb.y + zb.z * eb.z + zb.w * eb.w;
#pragma unroll
        for (int off = 32; off >= 1; off >>= 1) d += __shfl_xor(d, off);
        lg[t] = d / 0.07f;
    }
    float m = lg[0];
#pragma unroll
    for (int t = 1; t < 21; ++t) m = fmaxf(m, lg[t]);
    float s = 0.f;
#pragma unroll
    for (int t = 0; t < 21; ++t) s += expf(lg[t] - m);
    float loss = logf(s) + m - lg[0];
    if (lane == 0) atomicAdd(&acc[2], loss);
}

// ======================= finalize =======================
__global__ void finalize_kernel(const float* __restrict__ acc, float* __restrict__ out)
{
    int t = blockIdx.x * blockDim.x + threadIdx.x;
    if (t < 512) out[2 + t] = 0.f;              // z_rel row 0
    if (t == 0) {
        out[0] = acc[1] + acc[0];               // recon_loss + kl
        out[1] = acc[2];                        // loss_csl
    }
}

// ======================= launcher =======================
extern "C" void kernel_launch(void* const* d_in, const int* in_sizes, int n_in,
                              void* d_out, int out_size, void* d_ws, size_t ws_size,
                              hipStream_t stream)
{
    const float* logits   = (const float*)d_in[0];
    const int*   rels     = (const int*)  d_in[1];
    const float* rel_dict = (const float*)d_in[2];
    const float* fc1_w    = (const float*)d_in[3];
    const float* fc1_b    = (const float*)d_in[4];
    const float* fc2mu_w  = (const float*)d_in[5];
    const float* fc2mu_b  = (const float*)d_in[6];
    const float* fc2ls_w  = (const float*)d_in[7];
    const float* fc2ls_b  = (const float*)d_in[8];
    const float* fc3_w    = (const float*)d_in[9];
    const float* fc3_b    = (const float*)d_in[10];
    const float* fc4_w    = (const float*)d_in[11];
    const float* fc4_b    = (const float*)d_in[12];
    const float* qi1_w    = (const float*)d_in[13];
    const float* qi1_b    = (const float*)d_in[14];
    const float* qi2_w    = (const float*)d_in[15];
    const float* qi2_b    = (const float*)d_in[16];
    const float* qz1_w    = (const float*)d_in[17];
    const float* qz1_b    = (const float*)d_in[18];
    const float* qz2_w    = (const float*)d_in[19];
    const float* qz2_b    = (const float*)d_in[20];
    const float* eps1     = (const float*)d_in[21];
    const float* eps2     = (const float*)d_in[22];
    float* out = (float*)d_out;

    // ---- workspace carve (256B aligned) ----
    char* wsb = (char*)d_ws;
    size_t off = 0;
    auto alloc = [&](size_t bytes) -> void* {
        off = (off + 255) & ~(size_t)255;
        void* p = wsb + off;
        off += bytes;
        return p;
    };
    float* acc     = (float*)alloc(16);                 // [kl, recon, csl]
    int*   top_idx = (int*)  alloc((size_t)B * 3 * 4);
    int*   dis_idx = (int*)  alloc((size_t)B * 20 * 4);
    float* R       = (float*)alloc((size_t)NRELS * FEAT * 4);
    float* Eh      = (float*)alloc((size_t)NRELS * 512 * 4);
    float* E       = (float*)alloc((size_t)NRELS * 512 * 4);
    float* xcat    = (float*)alloc((size_t)B * 600 * 4);
    float* h1      = (float*)alloc((size_t)B * 300 * 4);
    float* mu      = (float*)alloc((size_t)B * 512 * 4);
    float* lsb     = (float*)alloc((size_t)B * 512 * 4);
    float* zcat    = (float*)alloc((size_t)B * 812 * 4);
    float* zb      = (float*)alloc((size_t)B * 512 * 4);
    float* h3      = (float*)alloc((size_t)B * 300 * 4);
    float* recon   = mu;    // mu/ls dead after sample_kernel -> reuse
    float* t1      = lsb;

    hipMemsetAsync(acc, 0, 16, stream);

    dim3 thr(16, 16);
    topk_kernel   <<<B / 4, 256, 0, stream>>>(logits, top_idx, dis_idx);
    gather_R      <<<NRELS, 128, 0, stream>>>(rels, rel_dict, R);
    gather_xcat   <<<B,     128, 0, stream>>>(rels, rel_dict, top_idx, xcat);

    // E = enc2(R) through qi1/qi2
    gemm_act<2><<<dim3(8, 8),  thr, 0, stream>>>(R,  qi1_w, qi1_b, Eh, NRELS, 512, 300);
    gemm_act<2><<<dim3(8, 8),  thr, 0, stream>>>(Eh, qi2_w, qi2_b, E,  NRELS, 512, 512);

    // VAE encoder
    gemm_act<1><<<dim3(5, 32), thr, 0, stream>>>(xcat, fc1_w, fc1_b, h1, B, 300, 600);
    gemm_act<0><<<dim3(8, 32), thr, 0, stream>>>(h1, fc2mu_w, fc2mu_b, mu,  B, 512, 300);
    gemm_act<0><<<dim3(8, 32), thr, 0, stream>>>(h1, fc2ls_w, fc2ls_b, lsb, B, 512, 300);

    sample_kernel  <<<1024, 256, 0, stream>>>(mu, lsb, eps1, eps2, zcat, zb, acc);
    pos1copy_kernel<<<512,  256, 0, stream>>>(xcat, zcat);

    // decoder
    gemm_act<1><<<dim3(5, 32), thr, 0, stream>>>(zcat, fc3_w, fc3_b, h3, B, 300, 812);
    gemm_act<3><<<dim3(5, 32), thr, 0, stream>>>(h3, fc4_w, fc4_b, recon, B, 300, 300);
    recon_loss_kernel<<<512, 256, 0, stream>>>(recon, xcat, acc);

    // qz encoder -> z_p straight into z_rel rows 1..B
    float* zp = out + 2 + 512;
    gemm_act<2><<<dim3(8, 32), thr, 0, stream>>>(zb, qz1_w, qz1_b, t1, B, 512, 512);
    gemm_act<2><<<dim3(8, 32), thr, 0, stream>>>(t1, qz2_w, qz2_b, zp, B, 512, 512);

    csl_kernel     <<<B / 4, 256, 0, stream>>>(zp, E, top_idx, dis_idx, acc);
    finalize_kernel<<<2, 256, 0, stream>>>(acc, out);
}

// Round 2
// 198.840 us; speedup vs baseline: 3.1807x; 3.1807x over previous
//
#include <hip/hip_runtime.h>
#include <math.h>

#define B      2048
#define NRELS  512
#define FEAT   300
#define LAT    512

typedef __attribute__((ext_vector_type(8))) short short8;
typedef __attribute__((ext_vector_type(4))) float f32x4;

__device__ inline short f2bf(float f) {
    union { float f; unsigned u; } v; v.f = f;
    unsigned u = v.u;
    u += 0x7fffu + ((u >> 16) & 1u);   // round-to-nearest-even
    return (short)(u >> 16);
}

// ======================= top-k / bottom-k =======================
__global__ __launch_bounds__(256) void topk_kernel(const float* __restrict__ logits,
                                                   int* __restrict__ top_idx,
                                                   int* __restrict__ dis_idx)
{
    int lane = threadIdx.x & 63;
    int row  = blockIdx.x * 4 + (threadIdx.x >> 6);
    const float* p = logits + (size_t)row * NRELS;
    float v[8];
#pragma unroll
    for (int j = 0; j < 8; ++j) v[j] = p[j * 64 + lane];

    float w[8];
#pragma unroll
    for (int j = 0; j < 8; ++j) w[j] = v[j];
    for (int t = 0; t < 20; ++t) {
        float bv = __builtin_inff(); int bi = 0x7fffffff;
#pragma unroll
        for (int j = 0; j < 8; ++j) {
            int idx = j * 64 + lane;
            if (w[j] < bv || (w[j] == bv && idx < bi)) { bv = w[j]; bi = idx; }
        }
#pragma unroll
        for (int off = 32; off >= 1; off >>= 1) {
            float ov = __shfl_xor(bv, off);
            int   oi = __shfl_xor(bi, off);
            if (ov < bv || (ov == bv && oi < bi)) { bv = ov; bi = oi; }
        }
        if ((bi & 63) == lane) w[bi >> 6] = __builtin_inff();
        if (lane == 0) dis_idx[row * 20 + t] = bi;
    }
#pragma unroll
    for (int j = 0; j < 8; ++j) w[j] = v[j];
    for (int t = 0; t < 3; ++t) {
        float bv = -__builtin_inff(); int bi = 0x7fffffff;
#pragma unroll
        for (int j = 0; j < 8; ++j) {
            int idx = j * 64 + lane;
            if (w[j] > bv || (w[j] == bv && idx < bi)) { bv = w[j]; bi = idx; }
        }
#pragma unroll
        for (int off = 32; off >= 1; off >>= 1) {
            float ov = __shfl_xor(bv, off);
            int   oi = __shfl_xor(bi, off);
            if (ov > bv || (ov == bv && oi < bi)) { bv = ov; bi = oi; }
        }
        if ((bi & 63) == lane) w[bi >> 6] = -__builtin_inff();
        if (lane == 0) top_idx[row * 3 + t] = bi;
    }
}

// ======================= gathers (emit bf16, zero-padded) =======================
__global__ void gather_R(const int* __restrict__ rels, const float* __restrict__ rel_dict,
                         short* __restrict__ R)   // [512][320] bf16
{
    int j = blockIdx.x;
    int id = rels[2 * j + 1];
    const float* src = rel_dict + (size_t)id * FEAT;
    for (int c = threadIdx.x; c < 320; c += blockDim.x)
        R[(size_t)j * 320 + c] = (c < FEAT) ? f2bf(src[c]) : (short)0;
}

__global__ void gather_xcat(const int* __restrict__ rels, const float* __restrict__ rel_dict,
                            const int* __restrict__ top_idx,
                            short* __restrict__ xcat,   // [2048][608] bf16: [x|pos1|pad8]
                            float* __restrict__ xf,     // [2048][300] f32 x (for recon loss)
                            short* __restrict__ zcat)   // [2048][832] bf16: pos1 into cols 512..811
{
    int b = blockIdx.x;
    int i0 = rels[2 * top_idx[b * 3 + 0] + 1];
    int i1 = rels[2 * top_idx[b * 3 + 1] + 1];
    int i2 = rels[2 * top_idx[b * 3 + 2] + 1];
    const float* r0 = rel_dict + (size_t)i0 * FEAT;
    const float* r1 = rel_dict + (size_t)i1 * FEAT;
    const float* r2 = rel_dict + (size_t)i2 * FEAT;
    short* xd  = xcat + (size_t)b * 608;
    short* zd  = zcat + (size_t)b * 832;
    float* xfd = xf   + (size_t)b * 300;
    for (int c = threadIdx.x; c < FEAT; c += blockDim.x) {
        float a = r0[c];
        float x = a * r1[c] * r2[c];
        xd[c]        = f2bf(x);
        xd[300 + c]  = f2bf(a);
        zd[512 + c]  = f2bf(a);
        xfd[c]       = x;
    }
    if (threadIdx.x < 8)  xd[600 + threadIdx.x] = 0;
    if (threadIdx.x < 20) zd[812 + threadIdx.x] = 0;
}

// ======================= weight convert: f32 [K][N] -> bf16 transposed [Npad][Kpad] ===
struct WDesc { const float* src; short* dst; int K, N, Kpad, Npad; };
struct WPack { WDesc d[9]; };

__global__ __launch_bounds__(256) void convertW(WPack p)
{
    WDesc w = p.d[blockIdx.y];
    int total = w.Npad * w.Kpad;
    for (int i = blockIdx.x * 256 + threadIdx.x; i < total; i += gridDim.x * 256) {
        int n = i / w.Kpad, k = i - n * w.Kpad;
        w.dst[i] = (n < w.N && k < w.K) ? f2bf(w.src[(size_t)k * w.N + n]) : (short)0;
    }
}

// ======================= MFMA bf16 GEMM =======================
// C[M][ldc] = act(A[M][Kpad] @ Bt[Npad][Kpad]^T + bias), tiles 64x64, BK=32.
// M mult of 64, Npad mult of 64 (= gridDim.x*64), Kpad mult of 32.
template<int ACT, int OUTF32>   // ACT: 0 none, 1 relu, 2 leaky0.2, 3 sigmoid
__global__ __launch_bounds__(256) void gemm_mfma(const short* __restrict__ A,
                                                 const short* __restrict__ Bt,
                                                 const float* __restrict__ bias,
                                                 void* __restrict__ Cv,
                                                 int Nreal, int Kpad, int ldc)
{
    __shared__ short As[64][56];   // 56 shorts = 112B row stride: 16B aligned, 2-way banks
    __shared__ short Bs[64][56];
    const int wave = threadIdx.x >> 6;
    const int lane = threadIdx.x & 63;
    const int row0 = blockIdx.y * 64;
    const int col0 = blockIdx.x * 64;

    const int sr = threadIdx.x >> 2;        // staging row 0..63
    const int sk = (threadIdx.x & 3) * 8;   // staging k offset
    const short* Ap = A  + (size_t)(row0 + sr) * Kpad + sk;
    const short* Bp = Bt + (size_t)(col0 + sr) * Kpad + sk;

    const int frow = lane & 15;
    const int fk   = (lane >> 4) * 8;

    f32x4 acc0 = {0.f,0.f,0.f,0.f}, acc1 = {0.f,0.f,0.f,0.f};
    f32x4 acc2 = {0.f,0.f,0.f,0.f}, acc3 = {0.f,0.f,0.f,0.f};

    for (int k0 = 0; k0 < Kpad; k0 += 32) {
        short8 av = *(const short8*)(Ap + k0);
        short8 bv = *(const short8*)(Bp + k0);
        *(short8*)&As[sr][sk] = av;
        *(short8*)&Bs[sr][sk] = bv;
        __syncthreads();
        short8 af = *(const short8*)&As[wave * 16 + frow][fk];
        short8 b0 = *(const short8*)&Bs[ 0 + frow][fk];
        short8 b1 = *(const short8*)&Bs[16 + frow][fk];
        short8 b2 = *(const short8*)&Bs[32 + frow][fk];
        short8 b3 = *(const short8*)&Bs[48 + frow][fk];
        acc0 = __builtin_amdgcn_mfma_f32_16x16x32_bf16(af, b0, acc0, 0, 0, 0);
        acc1 = __builtin_amdgcn_mfma_f32_16x16x32_bf16(af, b1, acc1, 0, 0, 0);
        acc2 = __builtin_amdgcn_mfma_f32_16x16x32_bf16(af, b2, acc2, 0, 0, 0);
        acc3 = __builtin_amdgcn_mfma_f32_16x16x32_bf16(af, b3, acc3, 0, 0, 0);
        __syncthreads();
    }

    const int orow = row0 + wave * 16 + (lane >> 4) * 4;   // + j
    f32x4 accs[4] = {acc0, acc1, acc2, acc3};
#pragma unroll
    for (int n0 = 0; n0 < 4; ++n0) {
        int col = col0 + n0 * 16 + frow;
        float bs = (col < Nreal) ? bias[col] : 0.f;
#pragma unroll
        for (int j = 0; j < 4; ++j) {
            float v = accs[n0][j] + bs;
            if (ACT == 1)      v = v > 0.f ? v : 0.f;
            else if (ACT == 2) v = v > 0.f ? v : 0.2f * v;
            else if (ACT == 3) v = 1.f / (1.f + expf(-v));
            size_t idx = (size_t)(orow + j) * ldc + col;
            if (OUTF32) ((float*)Cv)[idx] = v;
            else        ((short*)Cv)[idx] = f2bf(v);
        }
    }
}

// ======================= sampling + KL =======================
__global__ __launch_bounds__(256) void sample_kernel(const float* __restrict__ mu,
                                                     const float* __restrict__ ls,
                                                     const float* __restrict__ eps1,
                                                     const float* __restrict__ eps2,
                                                     short* __restrict__ zcat,  // bf16 cols 0..511
                                                     short* __restrict__ zb,    // bf16 [2048][512]
                                                     float* __restrict__ acc)
{
    float klsum = 0.f;
    const int total = B * LAT;
    for (int i = blockIdx.x * blockDim.x + threadIdx.x; i < total; i += gridDim.x * blockDim.x) {
        int r = i >> 9, c = i & 511;
        float m = mu[i], l = ls[i];
        float s = expf(l);
        zcat[(size_t)r * 832 + c] = f2bf(m + eps1[i] * s);
        zb[i]                     = f2bf(m + eps2[i] * s);
        klsum += -0.5f * (1.f + 2.f * l - m * m - expf(2.f * l));
    }
    __shared__ float red[256];
    red[threadIdx.x] = klsum;
    __syncthreads();
    for (int s = 128; s > 0; s >>= 1) {
        if (threadIdx.x < s) red[threadIdx.x] += red[threadIdx.x + s];
        __syncthreads();
    }
    if (threadIdx.x == 0) atomicAdd(&acc[0], red[0]);
}

// ======================= recon loss =======================
__global__ __launch_bounds__(256) void recon_loss_kernel(const float* __restrict__ recon, // [2048][320]
                                                         const float* __restrict__ xf,    // [2048][300]
                                                         float* __restrict__ acc)
{
    float sum = 0.f;
    const int total = B * FEAT;
    for (int i = blockIdx.x * blockDim.x + threadIdx.x; i < total; i += gridDim.x * blockDim.x) {
        int r = i / FEAT, c = i - r * FEAT;
        float d = recon[(size_t)r * 320 + c] - xf[i];
        sum += d * d;
    }
    __shared__ float red[256];
    red[threadIdx.x] = sum;
    __syncthreads();
    for (int s = 128; s > 0; s >>= 1) {
        if (threadIdx.x < s) red[threadIdx.x] += red[threadIdx.x + s];
        __syncthreads();
    }
    if (threadIdx.x == 0) atomicAdd(&acc[1], red[0]);
}

// ======================= contrastive loss =======================
__global__ __launch_bounds__(256) void csl_kernel(const float* __restrict__ zp,
                                                  const float* __restrict__ E,
                                                  const int* __restrict__ top_idx,
                                                  const int* __restrict__ dis_idx,
                                                  float* __restrict__ acc)
{
    int lane = threadIdx.x & 63;
    int r    = blockIdx.x * 4 + (threadIdx.x >> 6);
    const float* z = zp + (size_t)r * LAT;
    const float4 za = reinterpret_cast<const float4*>(z)[lane * 2 + 0];
    const float4 zb = reinterpret_cast<const float4*>(z)[lane * 2 + 1];

    int ids[21];
    ids[0] = top_idx[r * 3];
#pragma unroll
    for (int n = 0; n < 20; ++n) ids[n + 1] = dis_idx[r * 20 + n];

    float lg[21];
#pragma unroll
    for (int t = 0; t < 21; ++t) {
        const float* e = E + (size_t)ids[t] * LAT;
        const float4 ea = reinterpret_cast<const float4*>(e)[lane * 2 + 0];
        const float4 eb = reinterpret_cast<const float4*>(e)[lane * 2 + 1];
        float d = za.x * ea.x + za.y * ea.y + za.z * ea.z + za.w * ea.w
                + zb.x * eb.x + zb.y * eb.y + zb.z * eb.z + zb.w * eb.w;
#pragma unroll
        for (int off = 32; off >= 1; off >>= 1) d += __shfl_xor(d, off);
        lg[t] = d / 0.07f;
    }
    float m = lg[0];
#pragma unroll
    for (int t = 1; t < 21; ++t) m = fmaxf(m, lg[t]);
    float s = 0.f;
#pragma unroll
    for (int t = 0; t < 21; ++t) s += expf(lg[t] - m);
    float loss = logf(s) + m - lg[0];
    if (lane == 0) atomicAdd(&acc[2], loss);
}

// ======================= finalize =======================
__global__ void finalize_kernel(const float* __restrict__ acc, float* __restrict__ out)
{
    int t = blockIdx.x * blockDim.x + threadIdx.x;
    if (t < 512) out[2 + t] = 0.f;
    if (t == 0) {
        out[0] = acc[1] + acc[0];
        out[1] = acc[2];
    }
}

// ======================= launcher =======================
extern "C" void kernel_launch(void* const* d_in, const int* in_sizes, int n_in,
                              void* d_out, int out_size, void* d_ws, size_t ws_size,
                              hipStream_t stream)
{
    const float* logits   = (const float*)d_in[0];
    const int*   rels     = (const int*)  d_in[1];
    const float* rel_dict = (const float*)d_in[2];
    const float* fc1_w    = (const float*)d_in[3];
    const float* fc1_b    = (const float*)d_in[4];
    const float* fc2mu_w  = (const float*)d_in[5];
    const float* fc2mu_b  = (const float*)d_in[6];
    const float* fc2ls_w  = (const float*)d_in[7];
    const float* fc2ls_b  = (const float*)d_in[8];
    const float* fc3_w    = (const float*)d_in[9];
    const float* fc3_b    = (const float*)d_in[10];
    const float* fc4_w    = (const float*)d_in[11];
    const float* fc4_b    = (const float*)d_in[12];
    const float* qi1_w    = (const float*)d_in[13];
    const float* qi1_b    = (const float*)d_in[14];
    const float* qi2_w    = (const float*)d_in[15];
    const float* qi2_b    = (const float*)d_in[16];
    const float* qz1_w    = (const float*)d_in[17];
    const float* qz1_b    = (const float*)d_in[18];
    const float* qz2_w    = (const float*)d_in[19];
    const float* qz2_b    = (const float*)d_in[20];
    const float* eps1     = (const float*)d_in[21];
    const float* eps2     = (const float*)d_in[22];
    float* out = (float*)d_out;

    char* wsb = (char*)d_ws;
    size_t off = 0;
    auto alloc = [&](size_t bytes) -> void* {
        off = (off + 255) & ~(size_t)255;
        void* p = wsb + off;
        off += bytes;
        return p;
    };
    float* acc     = (float*)alloc(16);
    int*   top_idx = (int*)  alloc((size_t)B * 3 * 4);
    int*   dis_idx = (int*)  alloc((size_t)B * 20 * 4);
    short* Rb      = (short*)alloc((size_t)NRELS * 320 * 2);
    short* Ehb     = (short*)alloc((size_t)NRELS * 512 * 2);
    float* E       = (float*)alloc((size_t)NRELS * 512 * 4);
    short* xcat    = (short*)alloc((size_t)B * 608 * 2);
    float* xf      = (float*)alloc((size_t)B * 300 * 4);
    short* h1      = (short*)alloc((size_t)B * 320 * 2);
    float* mu      = (float*)alloc((size_t)B * 512 * 4);
    float* ls      = (float*)alloc((size_t)B * 512 * 4);
    short* zcat    = (short*)alloc((size_t)B * 832 * 2);
    short* zb      = (short*)alloc((size_t)B * 512 * 2);
    short* h3      = (short*)alloc((size_t)B * 320 * 2);
    float* recon   = mu;            // f32 [2048][320], mu dead after sample
    short* t1      = (short*)ls;    // bf16 [2048][512], ls dead after sample

    // bf16 transposed weights
    short* w_qi1t = (short*)alloc((size_t)512 * 320 * 2);
    short* w_qi2t = (short*)alloc((size_t)512 * 512 * 2);
    short* w_fc1t = (short*)alloc((size_t)320 * 608 * 2);
    short* w_mut  = (short*)alloc((size_t)512 * 320 * 2);
    short* w_lst  = (short*)alloc((size_t)512 * 320 * 2);
    short* w_fc3t = (short*)alloc((size_t)320 * 832 * 2);
    short* w_fc4t = (short*)alloc((size_t)320 * 320 * 2);
    short* w_qz1t = (short*)alloc((size_t)512 * 512 * 2);
    short* w_qz2t = (short*)alloc((size_t)512 * 512 * 2);

    hipMemsetAsync(acc, 0, 16, stream);

    WPack p;
    p.d[0] = {qi1_w,   w_qi1t, 300, 512, 320, 512};
    p.d[1] = {qi2_w,   w_qi2t, 512, 512, 512, 512};
    p.d[2] = {fc1_w,   w_fc1t, 600, 300, 608, 320};
    p.d[3] = {fc2mu_w, w_mut,  300, 512, 320, 512};
    p.d[4] = {fc2ls_w, w_lst,  300, 512, 320, 512};
    p.d[5] = {fc3_w,   w_fc3t, 812, 300, 832, 320};
    p.d[6] = {fc4_w,   w_fc4t, 300, 300, 320, 320};
    p.d[7] = {qz1_w,   w_qz1t, 512, 512, 512, 512};
    p.d[8] = {qz2_w,   w_qz2t, 512, 512, 512, 512};
    convertW<<<dim3(96, 9), 256, 0, stream>>>(p);

    topk_kernel <<<B / 4, 256, 0, stream>>>(logits, top_idx, dis_idx);
    gather_R    <<<NRELS, 128, 0, stream>>>(rels, rel_dict, Rb);
    gather_xcat <<<B,     128, 0, stream>>>(rels, rel_dict, top_idx, xcat, xf, zcat);

    // E = enc2(R) via qi1/qi2
    gemm_mfma<2,0><<<dim3(8, 8),  256, 0, stream>>>(Rb,   w_qi1t, qi1_b,   Ehb,  512, 320, 512);
    gemm_mfma<2,1><<<dim3(8, 8),  256, 0, stream>>>(Ehb,  w_qi2t, qi2_b,   E,    512, 512, 512);

    // VAE encoder
    gemm_mfma<1,0><<<dim3(5, 32), 256, 0, stream>>>(xcat, w_fc1t, fc1_b,   h1,   300, 608, 320);
    gemm_mfma<0,1><<<dim3(8, 32), 256, 0, stream>>>(h1,   w_mut,  fc2mu_b, mu,   512, 320, 512);
    gemm_mfma<0,1><<<dim3(8, 32), 256, 0, stream>>>(h1,   w_lst,  fc2ls_b, ls,   512, 320, 512);

    sample_kernel<<<1024, 256, 0, stream>>>(mu, ls, eps1, eps2, zcat, zb, acc);

    // decoder
    gemm_mfma<1,0><<<dim3(5, 32), 256, 0, stream>>>(zcat, w_fc3t, fc3_b,   h3,    300, 832, 320);
    gemm_mfma<3,1><<<dim3(5, 32), 256, 0, stream>>>(h3,   w_fc4t, fc4_b,   recon, 300, 320, 320);
    recon_loss_kernel<<<512, 256, 0, stream>>>(recon, xf, acc);

    // qz encoder -> z_p into z_rel rows 1..B
    float* zp = out + 2 + 512;
    gemm_mfma<2,0><<<dim3(8, 32), 256, 0, stream>>>(zb, w_qz1t, qz1_b, t1, 512, 512, 512);
    gemm_mfma<2,1><<<dim3(8, 32), 256, 0, stream>>>(t1, w_qz2t, qz2_b, zp, 512, 512, 512);

    csl_kernel     <<<B / 4, 256, 0, stream>>>(zp, E, top_idx, dis_idx, acc);
    finalize_kernel<<<2, 256, 0, stream>>>(acc, out);
}

// Round 3
// 159.170 us; speedup vs baseline: 3.9734x; 1.2492x over previous
//
#include <hip/hip_runtime.h>
#include <math.h>

#define B      2048
#define NRELS  512
#define FEAT   300
#define LAT    512

typedef __attribute__((ext_vector_type(8))) short short8;
typedef __attribute__((ext_vector_type(4))) float f32x4;

__device__ inline short f2bf(float f) {
    union { float f; unsigned u; } v; v.f = f;
    unsigned u = v.u;
    u += 0x7fffu + ((u >> 16) & 1u);   // RNE
    return (short)(u >> 16);
}

// ============ fused top-k / bottom-k + gathers ============
// 4 rows per block (one per wave). After selection, gather x/pos1 for this row.
__global__ __launch_bounds__(256) void topk_gather_kernel(const float* __restrict__ logits,
                                                          const int* __restrict__ rels,
                                                          const float* __restrict__ rel_dict,
                                                          int* __restrict__ top_idx,
                                                          int* __restrict__ dis_idx,
                                                          short* __restrict__ xcat,  // [B][640]
                                                          float* __restrict__ xf,    // [B][300]
                                                          short* __restrict__ zcat)  // [B][832]
{
    int lane = threadIdx.x & 63;
    int row  = blockIdx.x * 4 + (threadIdx.x >> 6);
    const float* p = logits + (size_t)row * NRELS;
    float v[8];
#pragma unroll
    for (int j = 0; j < 8; ++j) v[j] = p[j * 64 + lane];

    float w[8];
#pragma unroll
    for (int j = 0; j < 8; ++j) w[j] = v[j];
    for (int t = 0; t < 20; ++t) {
        float bv = __builtin_inff(); int bi = 0x7fffffff;
#pragma unroll
        for (int j = 0; j < 8; ++j) {
            int idx = j * 64 + lane;
            if (w[j] < bv || (w[j] == bv && idx < bi)) { bv = w[j]; bi = idx; }
        }
#pragma unroll
        for (int off = 32; off >= 1; off >>= 1) {
            float ov = __shfl_xor(bv, off);
            int   oi = __shfl_xor(bi, off);
            if (ov < bv || (ov == bv && oi < bi)) { bv = ov; bi = oi; }
        }
        if ((bi & 63) == lane) w[bi >> 6] = __builtin_inff();
        if (lane == 0) dis_idx[row * 20 + t] = bi;
    }
    int t3[3];
#pragma unroll
    for (int j = 0; j < 8; ++j) w[j] = v[j];
    for (int t = 0; t < 3; ++t) {
        float bv = -__builtin_inff(); int bi = 0x7fffffff;
#pragma unroll
        for (int j = 0; j < 8; ++j) {
            int idx = j * 64 + lane;
            if (w[j] > bv || (w[j] == bv && idx < bi)) { bv = w[j]; bi = idx; }
        }
#pragma unroll
        for (int off = 32; off >= 1; off >>= 1) {
            float ov = __shfl_xor(bv, off);
            int   oi = __shfl_xor(bi, off);
            if (ov > bv || (ov == bv && oi < bi)) { bv = ov; bi = oi; }
        }
        if ((bi & 63) == lane) w[bi >> 6] = -__builtin_inff();
        t3[t] = bi;
    }
    if (lane == 0) top_idx[row] = t3[0];

    // gather for this row
    int i0 = rels[2 * t3[0] + 1];
    int i1 = rels[2 * t3[1] + 1];
    int i2 = rels[2 * t3[2] + 1];
    const float* r0 = rel_dict + (size_t)i0 * FEAT;
    const float* r1 = rel_dict + (size_t)i1 * FEAT;
    const float* r2 = rel_dict + (size_t)i2 * FEAT;
    short* xd  = xcat + (size_t)row * 640;
    short* zd  = zcat + (size_t)row * 832;
    float* xfd = xf   + (size_t)row * 300;
    for (int c = lane; c < FEAT; c += 64) {
        float a = r0[c];
        float x = a * r1[c] * r2[c];
        xd[c]       = f2bf(x);
        xd[300 + c] = f2bf(a);
        zd[512 + c] = f2bf(a);
        xfd[c]      = x;
    }
    if (lane < 40) xd[600 + lane] = 0;
    if (lane < 20) zd[812 + lane] = 0;
}

// ============ gather R (per-relation features, bf16 padded) ============
__global__ void gather_R(const int* __restrict__ rels, const float* __restrict__ rel_dict,
                         short* __restrict__ R)   // [512][320]
{
    int j = blockIdx.x;
    int id = rels[2 * j + 1];
    const float* src = rel_dict + (size_t)id * FEAT;
    for (int c = threadIdx.x; c < 320; c += blockDim.x)
        R[(size_t)j * 320 + c] = (c < FEAT) ? f2bf(src[c]) : (short)0;
}

// ============ weight convert: f32 [K][N] -> bf16 transposed [Npad][Kpad] ============
struct WDesc { const float* src; short* dst; int K, N, Kpad, Npad; };
struct WPack { WDesc d[9]; };

__global__ __launch_bounds__(256) void convertW(WPack p, float* __restrict__ acc)
{
    if (blockIdx.x == 0 && blockIdx.y == 0 && threadIdx.x < 3) acc[threadIdx.x] = 0.f;
    WDesc w = p.d[blockIdx.y];
    int total = w.Npad * w.Kpad;
    for (int i = blockIdx.x * 256 + threadIdx.x; i < total; i += gridDim.x * 256) {
        int n = i / w.Kpad, k = i - n * w.Kpad;
        w.dst[i] = (n < w.N && k < w.K) ? f2bf(w.src[(size_t)k * w.N + n]) : (short)0;
    }
}

// ============ MFMA bf16 GEMM, BK=64, register-prefetch pipeline ============
// C[M][ldc] = act(A[M][Kpad] @ Bt[Npad][Kpad]^T + bias); tiles 64x64.
// M mult 64, Npad = gridDim.x*64, Kpad mult 64.
// FUSE=1: fc4 mode — no C write; sum_{col<Nreal} (sigmoid(v) - xf[row][col])^2 -> atomicAdd(accv).
template<int ACT, int OUTF32, int FUSE>   // ACT: 0 none, 1 relu, 2 leaky0.2, 3 sigmoid
__global__ __launch_bounds__(256) void gemm_mfma(const short* __restrict__ A,
                                                 const short* __restrict__ Bt,
                                                 const float* __restrict__ bias,
                                                 const float* __restrict__ bias2,
                                                 int nsplit,
                                                 void* __restrict__ Cv,
                                                 int Nreal, int Kpad, int ldc,
                                                 const float* __restrict__ xf,
                                                 float* __restrict__ accv)
{
    __shared__ short As[64][72];   // 144B row stride: 16B-aligned, worst 2-way banks (free)
    __shared__ short Bs[64][72];
    const int wave = threadIdx.x >> 6;
    const int lane = threadIdx.x & 63;
    const int row0 = blockIdx.y * 64;
    const int col0 = blockIdx.x * 64;

    // staging: thread t handles rows (t>>3) and (t>>3)+32 at k-offset (t&7)*8
    const int srow = threadIdx.x >> 3;
    const int sk   = (threadIdx.x & 7) * 8;
    const short* Ap0 = A  + (size_t)(row0 + srow)      * Kpad + sk;
    const short* Ap1 = A  + (size_t)(row0 + srow + 32) * Kpad + sk;
    const short* Bp0 = Bt + (size_t)(col0 + srow)      * Kpad + sk;
    const short* Bp1 = Bt + (size_t)(col0 + srow + 32) * Kpad + sk;

    const int frow = lane & 15;
    const int fk   = (lane >> 4) * 8;

    f32x4 acc0 = {0,0,0,0}, acc1 = {0,0,0,0}, acc2 = {0,0,0,0}, acc3 = {0,0,0,0};

    short8 a0 = *(const short8*)Ap0;
    short8 a1 = *(const short8*)Ap1;
    short8 b0 = *(const short8*)Bp0;
    short8 b1 = *(const short8*)Bp1;

    for (int k0 = 0; k0 < Kpad; k0 += 64) {
        *(short8*)&As[srow][sk]      = a0;
        *(short8*)&As[srow + 32][sk] = a1;
        *(short8*)&Bs[srow][sk]      = b0;
        *(short8*)&Bs[srow + 32][sk] = b1;
        __syncthreads();
        int kn = k0 + 64;
        if (kn < Kpad) {               // prefetch next tile; latency hides under MFMA phase
            a0 = *(const short8*)(Ap0 + kn);
            a1 = *(const short8*)(Ap1 + kn);
            b0 = *(const short8*)(Bp0 + kn);
            b1 = *(const short8*)(Bp1 + kn);
        }
        short8 af0 = *(const short8*)&As[wave * 16 + frow][fk];
        short8 af1 = *(const short8*)&As[wave * 16 + frow][fk + 32];
        short8 bf00 = *(const short8*)&Bs[ 0 + frow][fk];
        short8 bf01 = *(const short8*)&Bs[ 0 + frow][fk + 32];
        short8 bf10 = *(const short8*)&Bs[16 + frow][fk];
        short8 bf11 = *(const short8*)&Bs[16 + frow][fk + 32];
        short8 bf20 = *(const short8*)&Bs[32 + frow][fk];
        short8 bf21 = *(const short8*)&Bs[32 + frow][fk + 32];
        short8 bf30 = *(const short8*)&Bs[48 + frow][fk];
        short8 bf31 = *(const short8*)&Bs[48 + frow][fk + 32];
        acc0 = __builtin_amdgcn_mfma_f32_16x16x32_bf16(af0, bf00, acc0, 0, 0, 0);
        acc1 = __builtin_amdgcn_mfma_f32_16x16x32_bf16(af0, bf10, acc1, 0, 0, 0);
        acc2 = __builtin_amdgcn_mfma_f32_16x16x32_bf16(af0, bf20, acc2, 0, 0, 0);
        acc3 = __builtin_amdgcn_mfma_f32_16x16x32_bf16(af0, bf30, acc3, 0, 0, 0);
        acc0 = __builtin_amdgcn_mfma_f32_16x16x32_bf16(af1, bf01, acc0, 0, 0, 0);
        acc1 = __builtin_amdgcn_mfma_f32_16x16x32_bf16(af1, bf11, acc1, 0, 0, 0);
        acc2 = __builtin_amdgcn_mfma_f32_16x16x32_bf16(af1, bf21, acc2, 0, 0, 0);
        acc3 = __builtin_amdgcn_mfma_f32_16x16x32_bf16(af1, bf31, acc3, 0, 0, 0);
        __syncthreads();
    }

    const int orow = row0 + wave * 16 + (lane >> 4) * 4;
    f32x4 accs[4] = {acc0, acc1, acc2, acc3};
    float fsum = 0.f;
#pragma unroll
    for (int n0 = 0; n0 < 4; ++n0) {
        int col = col0 + n0 * 16 + frow;
        float bs = (col < nsplit) ? bias[col] : bias2[col - nsplit];
#pragma unroll
        for (int j = 0; j < 4; ++j) {
            float v = accs[n0][j] + bs;
            if (ACT == 1)      v = v > 0.f ? v : 0.f;
            else if (ACT == 2) v = v > 0.f ? v : 0.2f * v;
            else if (ACT == 3) v = 1.f / (1.f + expf(-v));
            if (FUSE) {
                if (col < Nreal) {
                    float d = v - xf[(size_t)(orow + j) * 300 + col];
                    fsum += d * d;
                }
            } else {
                size_t idx = (size_t)(orow + j) * ldc + col;
                if (OUTF32) ((float*)Cv)[idx] = v;
                else        ((short*)Cv)[idx] = f2bf(v);
            }
        }
    }
    if (FUSE) {
        // block-reduce fsum -> atomicAdd
#pragma unroll
        for (int off = 32; off >= 1; off >>= 1) fsum += __shfl_xor(fsum, off);
        __shared__ float red[4];
        if (lane == 0) red[wave] = fsum;
        __syncthreads();
        if (threadIdx.x == 0)
            atomicAdd(accv, red[0] + red[1] + red[2] + red[3]);
    }
}

// ============ sampling + KL ============
__global__ __launch_bounds__(256) void sample_kernel(const float* __restrict__ muls, // [B][1024]
                                                     const float* __restrict__ eps1,
                                                     const float* __restrict__ eps2,
                                                     short* __restrict__ zcat,
                                                     short* __restrict__ zb,
                                                     float* __restrict__ acc)
{
    float klsum = 0.f;
    const int total = B * LAT;
    for (int i = blockIdx.x * blockDim.x + threadIdx.x; i < total; i += gridDim.x * blockDim.x) {
        int r = i >> 9, c = i & 511;
        float m = muls[(size_t)r * 1024 + c];
        float l = muls[(size_t)r * 1024 + 512 + c];
        float s = expf(l);
        zcat[(size_t)r * 832 + c] = f2bf(m + eps1[i] * s);
        zb[i]                     = f2bf(m + eps2[i] * s);
        klsum += -0.5f * (1.f + 2.f * l - m * m - expf(2.f * l));
    }
    __shared__ float red[256];
    red[threadIdx.x] = klsum;
    __syncthreads();
    for (int s = 128; s > 0; s >>= 1) {
        if (threadIdx.x < s) red[threadIdx.x] += red[threadIdx.x + s];
        __syncthreads();
    }
    if (threadIdx.x == 0) atomicAdd(&acc[0], red[0]);
}

// ============ contrastive loss ============
__global__ __launch_bounds__(256) void csl_kernel(const float* __restrict__ zp,
                                                  const float* __restrict__ E,
                                                  const int* __restrict__ top_idx,
                                                  const int* __restrict__ dis_idx,
                                                  float* __restrict__ acc)
{
    int lane = threadIdx.x & 63;
    int r    = blockIdx.x * 4 + (threadIdx.x >> 6);
    const float* z = zp + (size_t)r * LAT;
    const float4 za = reinterpret_cast<const float4*>(z)[lane * 2 + 0];
    const float4 zb = reinterpret_cast<const float4*>(z)[lane * 2 + 1];

    int ids[21];
    ids[0] = top_idx[r];
#pragma unroll
    for (int n = 0; n < 20; ++n) ids[n + 1] = dis_idx[r * 20 + n];

    float lg[21];
#pragma unroll
    for (int t = 0; t < 21; ++t) {
        const float* e = E + (size_t)ids[t] * LAT;
        const float4 ea = reinterpret_cast<const float4*>(e)[lane * 2 + 0];
        const float4 eb = reinterpret_cast<const float4*>(e)[lane * 2 + 1];
        float d = za.x * ea.x + za.y * ea.y + za.z * ea.z + za.w * ea.w
                + zb.x * eb.x + zb.y * eb.y + zb.z * eb.z + zb.w * eb.w;
#pragma unroll
        for (int off = 32; off >= 1; off >>= 1) d += __shfl_xor(d, off);
        lg[t] = d / 0.07f;
    }
    float m = lg[0];
#pragma unroll
    for (int t = 1; t < 21; ++t) m = fmaxf(m, lg[t]);
    float s = 0.f;
#pragma unroll
    for (int t = 0; t < 21; ++t) s += expf(lg[t] - m);
    float loss = logf(s) + m - lg[0];
    if (lane == 0) atomicAdd(&acc[2], loss);
}

// ============ finalize ============
__global__ void finalize_kernel(const float* __restrict__ acc, float* __restrict__ out)
{
    int t = blockIdx.x * blockDim.x + threadIdx.x;
    if (t < 512) out[2 + t] = 0.f;
    if (t == 0) {
        out[0] = acc[1] + acc[0];
        out[1] = acc[2];
    }
}

// ============ launcher ============
extern "C" void kernel_launch(void* const* d_in, const int* in_sizes, int n_in,
                              void* d_out, int out_size, void* d_ws, size_t ws_size,
                              hipStream_t stream)
{
    const float* logits   = (const float*)d_in[0];
    const int*   rels     = (const int*)  d_in[1];
    const float* rel_dict = (const float*)d_in[2];
    const float* fc1_w    = (const float*)d_in[3];
    const float* fc1_b    = (const float*)d_in[4];
    const float* fc2mu_w  = (const float*)d_in[5];
    const float* fc2mu_b  = (const float*)d_in[6];
    const float* fc2ls_w  = (const float*)d_in[7];
    const float* fc2ls_b  = (const float*)d_in[8];
    const float* fc3_w    = (const float*)d_in[9];
    const float* fc3_b    = (const float*)d_in[10];
    const float* fc4_w    = (const float*)d_in[11];
    const float* fc4_b    = (const float*)d_in[12];
    const float* qi1_w    = (const float*)d_in[13];
    const float* qi1_b    = (const float*)d_in[14];
    const float* qi2_w    = (const float*)d_in[15];
    const float* qi2_b    = (const float*)d_in[16];
    const float* qz1_w    = (const float*)d_in[17];
    const float* qz1_b    = (const float*)d_in[18];
    const float* qz2_w    = (const float*)d_in[19];
    const float* qz2_b    = (const float*)d_in[20];
    const float* eps1     = (const float*)d_in[21];
    const float* eps2     = (const float*)d_in[22];
    float* out = (float*)d_out;

    char* wsb = (char*)d_ws;
    size_t off = 0;
    auto alloc = [&](size_t bytes) -> void* {
        off = (off + 255) & ~(size_t)255;
        void* p = wsb + off;
        off += bytes;
        return p;
    };
    float* acc     = (float*)alloc(16);                       // [kl, recon, csl]
    int*   top_idx = (int*)  alloc((size_t)B * 4);
    int*   dis_idx = (int*)  alloc((size_t)B * 20 * 4);
    short* Rb      = (short*)alloc((size_t)NRELS * 320 * 2);
    short* Ehb     = (short*)alloc((size_t)NRELS * 512 * 2);
    float* E       = (float*)alloc((size_t)NRELS * 512 * 4);
    short* xcat    = (short*)alloc((size_t)B * 640 * 2);
    float* xf      = (float*)alloc((size_t)B * 300 * 4);
    short* h1      = (short*)alloc((size_t)B * 320 * 2);
    float* muls    = (float*)alloc((size_t)B * 1024 * 4);
    short* zcat    = (short*)alloc((size_t)B * 832 * 2);
    short* zb      = (short*)alloc((size_t)B * 512 * 2);
    short* h3      = (short*)alloc((size_t)B * 320 * 2);
    short* t1      = (short*)muls;   // bf16 [B][512]; muls dead after sample

    short* w_qi1t  = (short*)alloc((size_t)512 * 320 * 2);
    short* w_qi2t  = (short*)alloc((size_t)512 * 512 * 2);
    short* w_fc1t  = (short*)alloc((size_t)320 * 640 * 2);
    short* w_mulst = (short*)alloc((size_t)1024 * 320 * 2);  // rows 0-511 mu, 512-1023 ls
    short* w_fc3t  = (short*)alloc((size_t)320 * 832 * 2);
    short* w_fc4t  = (short*)alloc((size_t)320 * 320 * 2);
    short* w_qz1t  = (short*)alloc((size_t)512 * 512 * 2);
    short* w_qz2t  = (short*)alloc((size_t)512 * 512 * 2);

    WPack p;
    p.d[0] = {qi1_w,   w_qi1t,              300,  512, 320,  512};
    p.d[1] = {qi2_w,   w_qi2t,              512,  512, 512,  512};
    p.d[2] = {fc1_w,   w_fc1t,              600,  300, 640,  320};
    p.d[3] = {fc2mu_w, w_mulst,             300,  512, 320,  512};
    p.d[4] = {fc2ls_w, w_mulst + 512 * 320, 300,  512, 320,  512};
    p.d[5] = {fc3_w,   w_fc3t,              812,  300, 832,  320};
    p.d[6] = {fc4_w,   w_fc4t,              300,  300, 320,  320};
    p.d[7] = {qz1_w,   w_qz1t,              512,  512, 512,  512};
    p.d[8] = {qz2_w,   w_qz2t,              512,  512, 512,  512};
    convertW<<<dim3(96, 9), 256, 0, stream>>>(p, acc);

    topk_gather_kernel<<<B / 4, 256, 0, stream>>>(logits, rels, rel_dict,
                                                  top_idx, dis_idx, xcat, xf, zcat);
    gather_R<<<NRELS, 128, 0, stream>>>(rels, rel_dict, Rb);

    const int BIG = 1 << 20;
    // E = enc2(R) via qi1/qi2
    gemm_mfma<2,0,0><<<dim3(8, 8),  256, 0, stream>>>(Rb,  w_qi1t, qi1_b, qi1_b, BIG, Ehb, 512, 320, 512, nullptr, nullptr);
    gemm_mfma<2,1,0><<<dim3(8, 8),  256, 0, stream>>>(Ehb, w_qi2t, qi2_b, qi2_b, BIG, E,   512, 512, 512, nullptr, nullptr);

    // VAE encoder
    gemm_mfma<1,0,0><<<dim3(5, 32), 256, 0, stream>>>(xcat, w_fc1t, fc1_b, fc1_b, BIG, h1, 300, 640, 320, nullptr, nullptr);
    gemm_mfma<0,1,0><<<dim3(16, 32),256, 0, stream>>>(h1, w_mulst, fc2mu_b, fc2ls_b, 512, muls, 1024, 320, 1024, nullptr, nullptr);

    sample_kernel<<<1024, 256, 0, stream>>>(muls, eps1, eps2, zcat, zb, acc);

    // decoder (+fused recon loss)
    gemm_mfma<1,0,0><<<dim3(5, 32), 256, 0, stream>>>(zcat, w_fc3t, fc3_b, fc3_b, BIG, h3, 300, 832, 320, nullptr, nullptr);
    gemm_mfma<3,0,1><<<dim3(5, 32), 256, 0, stream>>>(h3, w_fc4t, fc4_b, fc4_b, BIG, nullptr, 300, 320, 320, xf, acc + 1);

    // qz encoder -> z_p into z_rel rows 1..B
    float* zp = out + 2 + 512;
    gemm_mfma<2,0,0><<<dim3(8, 32), 256, 0, stream>>>(zb, w_qz1t, qz1_b, qz1_b, BIG, t1, 512, 512, 512, nullptr, nullptr);
    gemm_mfma<2,1,0><<<dim3(8, 32), 256, 0, stream>>>(t1, w_qz2t, qz2_b, qz2_b, BIG, zp, 512, 512, 512, nullptr, nullptr);

    csl_kernel     <<<B / 4, 256, 0, stream>>>(zp, E, top_idx, dis_idx, acc);
    finalize_kernel<<<2, 256, 0, stream>>>(acc, out);
}

// Round 4
// 97.746 us; speedup vs baseline: 6.4703x; 1.6284x over previous
//
#include <hip/hip_runtime.h>
#include <math.h>

#define B      2048
#define NRELS  512
#define FEAT   300
#define LAT    512

typedef __attribute__((ext_vector_type(8))) short short8;
typedef __attribute__((ext_vector_type(4))) float f32x4;

__device__ inline short f2bf(float f) {
    union { float f; unsigned u; } v; v.f = f;
    unsigned u = v.u;
    u += 0x7fffu + ((u >> 16) & 1u);   // RNE
    return (short)(u >> 16);
}

// ================= weight descriptors =================
struct WDesc { const float* src; short* dst; int K, N, Kpad, Npad, ilv, ilvoff; };
struct WPack { WDesc d[9]; };

// ================= STAGE 0: convertW + topk/gather + gather_R + zeros =================
__global__ __launch_bounds__(256) void stage0(WPack p,
                                              const float* __restrict__ logits,
                                              const int* __restrict__ rels,
                                              const float* __restrict__ rel_dict,
                                              int* __restrict__ top_idx,
                                              int* __restrict__ dis_idx,
                                              short* __restrict__ xcat,  // [B][640]
                                              float* __restrict__ xf,    // [B][300]
                                              short* __restrict__ zcat,  // [B][832]
                                              short* __restrict__ Rb,    // [512][320]
                                              float* __restrict__ acc,   // [4] (kl,recon,csl,cnt)
                                              float* __restrict__ out)
{
    const int bid = blockIdx.x;
    if (bid < 512) {
        // ---- topk + gather, 4 rows/block ----
        if (bid == 0 && threadIdx.x >= 252) ((unsigned*)acc)[threadIdx.x - 252] = 0u;
        int lane = threadIdx.x & 63;
        int row  = bid * 4 + (threadIdx.x >> 6);
        const float* pl = logits + (size_t)row * NRELS;
        float v[8];
#pragma unroll
        for (int j = 0; j < 8; ++j) v[j] = pl[j * 64 + lane];
        float w[8];
#pragma unroll
        for (int j = 0; j < 8; ++j) w[j] = v[j];
        for (int t = 0; t < 20; ++t) {
            float bv = __builtin_inff(); int bi = 0x7fffffff;
#pragma unroll
            for (int j = 0; j < 8; ++j) {
                int idx = j * 64 + lane;
                if (w[j] < bv || (w[j] == bv && idx < bi)) { bv = w[j]; bi = idx; }
            }
#pragma unroll
            for (int off = 32; off >= 1; off >>= 1) {
                float ov = __shfl_xor(bv, off);
                int   oi = __shfl_xor(bi, off);
                if (ov < bv || (ov == bv && oi < bi)) { bv = ov; bi = oi; }
            }
            if ((bi & 63) == lane) w[bi >> 6] = __builtin_inff();
            if (lane == 0) dis_idx[row * 20 + t] = bi;
        }
        int t3[3];
#pragma unroll
        for (int j = 0; j < 8; ++j) w[j] = v[j];
        for (int t = 0; t < 3; ++t) {
            float bv = -__builtin_inff(); int bi = 0x7fffffff;
#pragma unroll
            for (int j = 0; j < 8; ++j) {
                int idx = j * 64 + lane;
                if (w[j] > bv || (w[j] == bv && idx < bi)) { bv = w[j]; bi = idx; }
            }
#pragma unroll
            for (int off = 32; off >= 1; off >>= 1) {
                float ov = __shfl_xor(bv, off);
                int   oi = __shfl_xor(bi, off);
                if (ov > bv || (ov == bv && oi < bi)) { bv = ov; bi = oi; }
            }
            if ((bi & 63) == lane) w[bi >> 6] = -__builtin_inff();
            t3[t] = bi;
        }
        if (lane == 0) top_idx[row] = t3[0];
        int i0 = rels[2 * t3[0] + 1];
        int i1 = rels[2 * t3[1] + 1];
        int i2 = rels[2 * t3[2] + 1];
        const float* r0 = rel_dict + (size_t)i0 * FEAT;
        const float* r1 = rel_dict + (size_t)i1 * FEAT;
        const float* r2 = rel_dict + (size_t)i2 * FEAT;
        short* xd  = xcat + (size_t)row * 640;
        short* zd  = zcat + (size_t)row * 832;
        float* xfd = xf   + (size_t)row * 300;
        for (int c = lane; c < FEAT; c += 64) {
            float a = r0[c];
            float x = a * r1[c] * r2[c];
            xd[c]       = f2bf(x);
            xd[300 + c] = f2bf(a);
            zd[512 + c] = f2bf(a);
            xfd[c]      = x;
        }
        if (lane < 40) xd[600 + lane] = 0;
        if (lane < 20) zd[812 + lane] = 0;
    } else if (bid < 640) {
        // ---- gather_R, 4 rels/block ----
        int lane = threadIdx.x & 63;
        int j = (bid - 512) * 4 + (threadIdx.x >> 6);
        int id = rels[2 * j + 1];
        const float* src = rel_dict + (size_t)id * FEAT;
        for (int c = lane; c < 320; c += 64)
            Rb[(size_t)j * 320 + c] = (c < FEAT) ? f2bf(src[c]) : (short)0;
    } else if (bid < 928) {
        // ---- convertW: 32 blocks/desc ----
        int rel = bid - 640;
        WDesc w = p.d[rel >> 5];
        int b32 = rel & 31;
        if (!w.ilv) {
            int total = w.Npad * w.Kpad;
            for (int i = b32 * 256 + threadIdx.x; i < total; i += 32 * 256) {
                int n = i / w.Kpad, k = i - n * w.Kpad;
                w.dst[i] = (n < w.N && k < w.K) ? f2bf(w.src[(size_t)k * w.N + n]) : (short)0;
            }
        } else {
            int total = w.N * w.Kpad;   // 512*320
            for (int i = b32 * 256 + threadIdx.x; i < total; i += 32 * 256) {
                int c = i / w.Kpad, k = i - c * w.Kpad;
                int n = ((c >> 5) << 6) + w.ilvoff + (c & 31);
                w.dst[(size_t)n * w.Kpad + k] = (k < w.K) ? f2bf(w.src[(size_t)k * w.N + c]) : (short)0;
            }
        }
    } else {
        // ---- zero z_rel row 0 ----
        out[2 + threadIdx.x]       = 0.f;
        out[2 + 256 + threadIdx.x] = 0.f;
    }
}

// ================= MFMA GEMM core (64x64 tile, BK=64, reg prefetch) =================
// MODE: 0 = store bf16, 1 = store f32, 2 = fc4 sigmoid+recon-loss fuse, 3 = mu/ls sample fuse
template<int ACT, int MODE>   // ACT: 0 none, 1 relu, 2 leaky0.2, 3 sigmoid
__device__ __attribute__((always_inline)) void gemm_core(
    short (&As)[64][72], short (&Bs)[64][72],
    int bx, int by,
    const short* __restrict__ A, const short* __restrict__ Bt,
    const float* __restrict__ bias, const float* __restrict__ bias2,
    void* __restrict__ Cv, int Nreal, int Kpad, int ldc,
    const float* __restrict__ aux0, const float* __restrict__ aux1,
    short* __restrict__ z0, short* __restrict__ z1,
    float* __restrict__ accv)
{
    const int wave = threadIdx.x >> 6;
    const int lane = threadIdx.x & 63;
    const int row0 = by * 64;
    const int col0 = bx * 64;

    const int srow = threadIdx.x >> 3;
    const int sk   = (threadIdx.x & 7) * 8;
    const short* Ap0 = A  + (size_t)(row0 + srow)      * Kpad + sk;
    const short* Ap1 = A  + (size_t)(row0 + srow + 32) * Kpad + sk;
    const short* Bp0 = Bt + (size_t)(col0 + srow)      * Kpad + sk;
    const short* Bp1 = Bt + (size_t)(col0 + srow + 32) * Kpad + sk;

    const int frow = lane & 15;
    const int fk   = (lane >> 4) * 8;

    f32x4 acc0 = {0,0,0,0}, acc1 = {0,0,0,0}, acc2 = {0,0,0,0}, acc3 = {0,0,0,0};

    short8 a0 = *(const short8*)Ap0;
    short8 a1 = *(const short8*)Ap1;
    short8 b0 = *(const short8*)Bp0;
    short8 b1 = *(const short8*)Bp1;

    for (int k0 = 0; k0 < Kpad; k0 += 64) {
        *(short8*)&As[srow][sk]      = a0;
        *(short8*)&As[srow + 32][sk] = a1;
        *(short8*)&Bs[srow][sk]      = b0;
        *(short8*)&Bs[srow + 32][sk] = b1;
        __syncthreads();
        int kn = k0 + 64;
        if (kn < Kpad) {
            a0 = *(const short8*)(Ap0 + kn);
            a1 = *(const short8*)(Ap1 + kn);
            b0 = *(const short8*)(Bp0 + kn);
            b1 = *(const short8*)(Bp1 + kn);
        }
        short8 af0 = *(const short8*)&As[wave * 16 + frow][fk];
        short8 af1 = *(const short8*)&As[wave * 16 + frow][fk + 32];
        short8 bf00 = *(const short8*)&Bs[ 0 + frow][fk];
        short8 bf01 = *(const short8*)&Bs[ 0 + frow][fk + 32];
        short8 bf10 = *(const short8*)&Bs[16 + frow][fk];
        short8 bf11 = *(const short8*)&Bs[16 + frow][fk + 32];
        short8 bf20 = *(const short8*)&Bs[32 + frow][fk];
        short8 bf21 = *(const short8*)&Bs[32 + frow][fk + 32];
        short8 bf30 = *(const short8*)&Bs[48 + frow][fk];
        short8 bf31 = *(const short8*)&Bs[48 + frow][fk + 32];
        acc0 = __builtin_amdgcn_mfma_f32_16x16x32_bf16(af0, bf00, acc0, 0, 0, 0);
        acc1 = __builtin_amdgcn_mfma_f32_16x16x32_bf16(af0, bf10, acc1, 0, 0, 0);
        acc2 = __builtin_amdgcn_mfma_f32_16x16x32_bf16(af0, bf20, acc2, 0, 0, 0);
        acc3 = __builtin_amdgcn_mfma_f32_16x16x32_bf16(af0, bf30, acc3, 0, 0, 0);
        acc0 = __builtin_amdgcn_mfma_f32_16x16x32_bf16(af1, bf01, acc0, 0, 0, 0);
        acc1 = __builtin_amdgcn_mfma_f32_16x16x32_bf16(af1, bf11, acc1, 0, 0, 0);
        acc2 = __builtin_amdgcn_mfma_f32_16x16x32_bf16(af1, bf21, acc2, 0, 0, 0);
        acc3 = __builtin_amdgcn_mfma_f32_16x16x32_bf16(af1, bf31, acc3, 0, 0, 0);
        __syncthreads();
    }

    const int orow = row0 + wave * 16 + (lane >> 4) * 4;
    f32x4 accs[4] = {acc0, acc1, acc2, acc3};

    if (MODE == 3) {
        // interleaved mu/ls -> z, z_, kl.  accs[n0] = mu half, accs[n0+2] = ls half.
        float kls = 0.f;
#pragma unroll
        for (int n0 = 0; n0 < 2; ++n0) {
            int zc = bx * 32 + n0 * 16 + frow;
            float bmu = bias[zc];
            float bls = bias2[zc];
#pragma unroll
            for (int j = 0; j < 4; ++j) {
                int row = orow + j;
                float m = accs[n0][j]     + bmu;
                float l = accs[n0 + 2][j] + bls;
                float s = expf(l);
                size_t ei = (size_t)row * 512 + zc;
                z0[(size_t)row * 832 + zc] = f2bf(m + aux0[ei] * s);
                z1[ei]                     = f2bf(m + aux1[ei] * s);
                kls += -0.5f * (1.f + 2.f * l - m * m - expf(2.f * l));
            }
        }
#pragma unroll
        for (int off = 32; off >= 1; off >>= 1) kls += __shfl_xor(kls, off);
        __shared__ float redS[4];
        if (lane == 0) redS[wave] = kls;
        __syncthreads();
        if (threadIdx.x == 0) atomicAdd(accv, redS[0] + redS[1] + redS[2] + redS[3]);
        return;
    }

    float fsum = 0.f;
#pragma unroll
    for (int n0 = 0; n0 < 4; ++n0) {
        int col = col0 + n0 * 16 + frow;
        float bs = bias[col < Nreal ? col : Nreal - 1];
#pragma unroll
        for (int j = 0; j < 4; ++j) {
            float v = accs[n0][j] + bs;
            if (ACT == 1)      v = v > 0.f ? v : 0.f;
            else if (ACT == 2) v = v > 0.f ? v : 0.2f * v;
            else if (ACT == 3) v = 1.f / (1.f + expf(-v));
            if (MODE == 2) {
                if (col < Nreal) {
                    float d = v - aux0[(size_t)(orow + j) * 300 + col];
                    fsum += d * d;
                }
            } else {
                size_t idx = (size_t)(orow + j) * ldc + col;
                if (MODE == 1) ((float*)Cv)[idx] = v;
                else           ((short*)Cv)[idx] = f2bf(v);
            }
        }
    }
    if (MODE == 2) {
#pragma unroll
        for (int off = 32; off >= 1; off >>= 1) fsum += __shfl_xor(fsum, off);
        __shared__ float redF[4];
        if (lane == 0) redF[wave] = fsum;
        __syncthreads();
        if (threadIdx.x == 0) atomicAdd(accv, redF[0] + redF[1] + redF[2] + redF[3]);
    }
}

// ================= stages 1-4 =================
__global__ __launch_bounds__(256) void stage1(const short* Rb, const short* w_qi1t, const float* qi1_b, short* Ehb,
                                              const short* xcat, const short* w_fc1t, const float* fc1_b, short* h1)
{
    __shared__ short As[64][72];
    __shared__ short Bs[64][72];
    int b = blockIdx.x;
    if (b < 64)
        gemm_core<2,0>(As, Bs, b & 7, b >> 3, Rb, w_qi1t, qi1_b, qi1_b, Ehb, 512, 320, 512,
                       nullptr, nullptr, nullptr, nullptr, nullptr);
    else {
        b -= 64;
        gemm_core<1,0>(As, Bs, b % 5, b / 5, xcat, w_fc1t, fc1_b, fc1_b, h1, 300, 640, 320,
                       nullptr, nullptr, nullptr, nullptr, nullptr);
    }
}

__global__ __launch_bounds__(256) void stage2(const short* Ehb, const short* w_qi2t, const float* qi2_b, float* E,
                                              const short* h1, const short* w_mulst,
                                              const float* mu_b, const float* ls_b,
                                              const float* eps1, const float* eps2,
                                              short* zcat, short* zb, float* acc)
{
    __shared__ short As[64][72];
    __shared__ short Bs[64][72];
    int b = blockIdx.x;
    if (b < 64)
        gemm_core<2,1>(As, Bs, b & 7, b >> 3, Ehb, w_qi2t, qi2_b, qi2_b, E, 512, 512, 512,
                       nullptr, nullptr, nullptr, nullptr, nullptr);
    else {
        b -= 64;
        gemm_core<0,3>(As, Bs, b & 15, b >> 4, h1, w_mulst, mu_b, ls_b, nullptr, 1024, 320, 0,
                       eps1, eps2, zcat, zb, acc);
    }
}

__global__ __launch_bounds__(256) void stage3(const short* zcat, const short* w_fc3t, const float* fc3_b, short* h3,
                                              const short* zb, const short* w_qz1t, const float* qz1_b, short* t1)
{
    __shared__ short As[64][72];
    __shared__ short Bs[64][72];
    int b = blockIdx.x;
    if (b < 160)
        gemm_core<1,0>(As, Bs, b % 5, b / 5, zcat, w_fc3t, fc3_b, fc3_b, h3, 300, 832, 320,
                       nullptr, nullptr, nullptr, nullptr, nullptr);
    else {
        b -= 160;
        gemm_core<2,0>(As, Bs, b & 7, b >> 3, zb, w_qz1t, qz1_b, qz1_b, t1, 512, 512, 512,
                       nullptr, nullptr, nullptr, nullptr, nullptr);
    }
}

__global__ __launch_bounds__(256) void stage4(const short* h3, const short* w_fc4t, const float* fc4_b,
                                              const float* xf, float* acc,
                                              const short* t1, const short* w_qz2t, const float* qz2_b, float* zp)
{
    __shared__ short As[64][72];
    __shared__ short Bs[64][72];
    int b = blockIdx.x;
    if (b < 160)
        gemm_core<3,2>(As, Bs, b % 5, b / 5, h3, w_fc4t, fc4_b, fc4_b, nullptr, 300, 320, 0,
                       xf, nullptr, nullptr, nullptr, acc + 1);
    else {
        b -= 160;
        gemm_core<2,1>(As, Bs, b & 7, b >> 3, t1, w_qz2t, qz2_b, qz2_b, zp, 512, 512, 512,
                       nullptr, nullptr, nullptr, nullptr, nullptr);
    }
}

// ================= STAGE 5: contrastive loss + finalize =================
__global__ __launch_bounds__(256) void stage5(const float* __restrict__ zp,
                                              const float* __restrict__ E,
                                              const int* __restrict__ top_idx,
                                              const int* __restrict__ dis_idx,
                                              float* __restrict__ acc,
                                              float* __restrict__ out)
{
    int lane = threadIdx.x & 63;
    int wave = threadIdx.x >> 6;
    int r    = blockIdx.x * 4 + wave;
    const float* z = zp + (size_t)r * LAT;
    const float4 za = reinterpret_cast<const float4*>(z)[lane * 2 + 0];
    const float4 zb = reinterpret_cast<const float4*>(z)[lane * 2 + 1];

    int ids[21];
    ids[0] = top_idx[r];
#pragma unroll
    for (int n = 0; n < 20; ++n) ids[n + 1] = dis_idx[r * 20 + n];

    float lg[21];
#pragma unroll
    for (int t = 0; t < 21; ++t) {
        const float* e = E + (size_t)ids[t] * LAT;
        const float4 ea = reinterpret_cast<const float4*>(e)[lane * 2 + 0];
        const float4 eb = reinterpret_cast<const float4*>(e)[lane * 2 + 1];
        float d = za.x * ea.x + za.y * ea.y + za.z * ea.z + za.w * ea.w
                + zb.x * eb.x + zb.y * eb.y + zb.z * eb.z + zb.w * eb.w;
#pragma unroll
        for (int off = 32; off >= 1; off >>= 1) d += __shfl_xor(d, off);
        lg[t] = d / 0.07f;
    }
    float m = lg[0];
#pragma unroll
    for (int t = 1; t < 21; ++t) m = fmaxf(m, lg[t]);
    float s = 0.f;
#pragma unroll
    for (int t = 0; t < 21; ++t) s += expf(lg[t] - m);
    float loss = logf(s) + m - lg[0];

    __shared__ float red[4];
    if (lane == 0) red[wave] = loss;
    __syncthreads();
    if (threadIdx.x == 0) {
        atomicAdd(&acc[2], red[0] + red[1] + red[2] + red[3]);
        __threadfence();
        unsigned old = atomicAdd((unsigned*)acc + 3, 1u);
        if (old == (unsigned)(gridDim.x - 1)) {
            __threadfence();
            volatile float* va = acc;
            out[0] = va[0] + va[1];   // kl + recon
            out[1] = va[2];           // csl
        }
    }
}

// ================= launcher =================
extern "C" void kernel_launch(void* const* d_in, const int* in_sizes, int n_in,
                              void* d_out, int out_size, void* d_ws, size_t ws_size,
                              hipStream_t stream)
{
    const float* logits   = (const float*)d_in[0];
    const int*   rels     = (const int*)  d_in[1];
    const float* rel_dict = (const float*)d_in[2];
    const float* fc1_w    = (const float*)d_in[3];
    const float* fc1_b    = (const float*)d_in[4];
    const float* fc2mu_w  = (const float*)d_in[5];
    const float* fc2mu_b  = (const float*)d_in[6];
    const float* fc2ls_w  = (const float*)d_in[7];
    const float* fc2ls_b  = (const float*)d_in[8];
    const float* fc3_w    = (const float*)d_in[9];
    const float* fc3_b    = (const float*)d_in[10];
    const float* fc4_w    = (const float*)d_in[11];
    const float* fc4_b    = (const float*)d_in[12];
    const float* qi1_w    = (const float*)d_in[13];
    const float* qi1_b    = (const float*)d_in[14];
    const float* qi2_w    = (const float*)d_in[15];
    const float* qi2_b    = (const float*)d_in[16];
    const float* qz1_w    = (const float*)d_in[17];
    const float* qz1_b    = (const float*)d_in[18];
    const float* qz2_w    = (const float*)d_in[19];
    const float* qz2_b    = (const float*)d_in[20];
    const float* eps1     = (const float*)d_in[21];
    const float* eps2     = (const float*)d_in[22];
    float* out = (float*)d_out;

    char* wsb = (char*)d_ws;
    size_t off = 0;
    auto alloc = [&](size_t bytes) -> void* {
        off = (off + 255) & ~(size_t)255;
        void* p = wsb + off;
        off += bytes;
        return p;
    };
    float* acc     = (float*)alloc(16);                       // kl, recon, csl, cnt
    int*   top_idx = (int*)  alloc((size_t)B * 4);
    int*   dis_idx = (int*)  alloc((size_t)B * 20 * 4);
    short* Rb      = (short*)alloc((size_t)NRELS * 320 * 2);
    short* Ehb     = (short*)alloc((size_t)NRELS * 512 * 2);
    float* E       = (float*)alloc((size_t)NRELS * 512 * 4);
    short* xcat    = (short*)alloc((size_t)B * 640 * 2);
    float* xf      = (float*)alloc((size_t)B * 300 * 4);
    short* h1      = (short*)alloc((size_t)B * 320 * 2);
    short* zcat    = (short*)alloc((size_t)B * 832 * 2);
    short* zb      = (short*)alloc((size_t)B * 512 * 2);
    short* h3      = (short*)alloc((size_t)B * 320 * 2);
    short* t1      = (short*)alloc((size_t)B * 512 * 2);

    short* w_qi1t  = (short*)alloc((size_t)512 * 320 * 2);
    short* w_qi2t  = (short*)alloc((size_t)512 * 512 * 2);
    short* w_fc1t  = (short*)alloc((size_t)320 * 640 * 2);
    short* w_mulst = (short*)alloc((size_t)1024 * 320 * 2);  // interleaved mu/ls
    short* w_fc3t  = (short*)alloc((size_t)320 * 832 * 2);
    short* w_fc4t  = (short*)alloc((size_t)320 * 320 * 2);
    short* w_qz1t  = (short*)alloc((size_t)512 * 512 * 2);
    short* w_qz2t  = (short*)alloc((size_t)512 * 512 * 2);

    WPack p;
    p.d[0] = {qi1_w,   w_qi1t,  300, 512, 320,  512, 0, 0};
    p.d[1] = {qi2_w,   w_qi2t,  512, 512, 512,  512, 0, 0};
    p.d[2] = {fc1_w,   w_fc1t,  600, 300, 640,  320, 0, 0};
    p.d[3] = {fc2mu_w, w_mulst, 300, 512, 320, 1024, 1, 0};
    p.d[4] = {fc2ls_w, w_mulst, 300, 512, 320, 1024, 1, 32};
    p.d[5] = {fc3_w,   w_fc3t,  812, 300, 832,  320, 0, 0};
    p.d[6] = {fc4_w,   w_fc4t,  300, 300, 320,  320, 0, 0};
    p.d[7] = {qz1_w,   w_qz1t,  512, 512, 512,  512, 0, 0};
    p.d[8] = {qz2_w,   w_qz2t,  512, 512, 512,  512, 0, 0};

    float* zp = out + 2 + 512;   // z_rel rows 1..B

    stage0<<<929, 256, 0, stream>>>(p, logits, rels, rel_dict, top_idx, dis_idx,
                                    xcat, xf, zcat, Rb, acc, out);
    stage1<<<224, 256, 0, stream>>>(Rb, w_qi1t, qi1_b, Ehb, xcat, w_fc1t, fc1_b, h1);
    stage2<<<576, 256, 0, stream>>>(Ehb, w_qi2t, qi2_b, E, h1, w_mulst, fc2mu_b, fc2ls_b,
                                    eps1, eps2, zcat, zb, acc);
    stage3<<<416, 256, 0, stream>>>(zcat, w_fc3t, fc3_b, h3, zb, w_qz1t, qz1_b, t1);
    stage4<<<416, 256, 0, stream>>>(h3, w_fc4t, fc4_b, xf, acc, t1, w_qz2t, qz2_b, zp);
    stage5<<<B / 4, 256, 0, stream>>>(zp, E, top_idx, dis_idx, acc, out);
}